// Round 1
// baseline (342.135 us; speedup 1.0000x reference)
//
#include <hip/hip_runtime.h>

// MemoryGraph: B=8, NC=256, Nc=128, D_n=64, HS=256, HM=128, ALPHA=2
// One block per (b,c) cell; 4 waves; each wave owns 32 neuron rows.
// All matmuls via v_mfma_f32_16x16x32_bf16 (f32 accum).

#define NCELL 256

typedef __attribute__((ext_vector_type(8))) short bf16x8;
typedef __attribute__((ext_vector_type(4))) float f32x4;

#define MFMA(a, b, c) __builtin_amdgcn_mfma_f32_16x16x32_bf16((a), (b), (c), 0, 0, 0)

__device__ __forceinline__ unsigned short f2bf(float f) {
    unsigned u = __builtin_bit_cast(unsigned, f);
    u = (u + 0x7FFFu + ((u >> 16) & 1u)) >> 16;   // RNE
    return (unsigned short)u;
}
__device__ __forceinline__ float bf2f(unsigned short b) {
    unsigned u = ((unsigned)b) << 16;
    return __builtin_bit_cast(float, u);
}
__device__ __forceinline__ float sigm(float v) { return 1.0f / (1.0f + __expf(-v)); }

// Swizzled LDS index helpers (ushort units). 16B-granule XOR swizzle on row.
__device__ __forceinline__ int sw64(int row, int col) {   // [R][64] bf16 tile
    return row * 64 + ((((col >> 3) ^ row) & 7) << 3) + (col & 7);
}
__device__ __forceinline__ int sw128(int row, int col) {  // [R][128] bf16 tile
    return row * 128 + (((col >> 3) ^ (row & 7)) << 3) + (col & 7);
}
__device__ __forceinline__ int sw32(int row, int col) {   // [32][32] bf16 tile
    return row * 32 + ((((col >> 3) ^ row) & 3) << 3) + (col & 7);
}

__global__ void cvt_w(const float* __restrict__ a, const float* __restrict__ b,
                      const float* __restrict__ c, const float* __restrict__ d,
                      unsigned short* __restrict__ dst) {
    int i = blockIdx.x * 256 + threadIdx.x;   // 65536 total
    float v;
    if (i < 8192) v = a[i];                    // msg_w1 [128][64]
    else if (i < 16384) v = b[i - 8192];       // msg_w2 [64][128]
    else if (i < 49152) v = c[i - 16384];      // state_w1 [256][128]
    else v = d[i - 49152];                     // state_w2 [64][256]
    dst[i] = f2bf(v);
}

__global__ __launch_bounds__(256, 2)
void cell_kernel(const float* __restrict__ x, const float* __restrict__ h,
                 const float* __restrict__ W, const float* __restrict__ decay,
                 const float* __restrict__ hebb, const float* __restrict__ nid,
                 const float* __restrict__ sb1, const float* __restrict__ sb2,
                 const float* __restrict__ mb1, const float* __restrict__ mb2,
                 const float* __restrict__ injw, const float* __restrict__ injb,
                 const float* __restrict__ wdl, const float* __restrict__ dgl,
                 const float* __restrict__ hdl,
                 const unsigned short* __restrict__ wbf,
                 float* __restrict__ out) {
    const int cell = blockIdx.x;              // b*NC + c
    const int c = cell & (NCELL - 1);
    const int tid = threadIdx.x;
    const int wv = tid >> 6;
    const int lane = tid & 63;
    const int lr = lane & 15;                 // A-row / B-col / C-col lane
    const int lg = lane >> 4;                 // k-group / C-row group

    float* out_h  = out;
    float* out_m  = out + 16777216;
    float* out_W  = out + 33554432;
    float* out_d  = out + 67108864;
    float* out_hb = out + 67371008;

    const unsigned short* w1m = wbf;              // [128][64]
    const unsigned short* w2m = wbf + 8192;       // [64][128]
    const unsigned short* w1s = wbf + 16384;      // [256][128]
    const unsigned short* w2s = wbf + 49152;      // [64][256]

    __shared__ alignas(16) unsigned char smem[73728];        // 72 KB
    unsigned short* hid_s = (unsigned short*)smem;           // [128][64] h_id, later h_new
    unsigned short* m_s   = (unsigned short*)(smem + 16384); // [128][64] m (j-major)
    unsigned short* mT_s  = (unsigned short*)(smem + 32768); // [64][128] m^T (d-major)
    unsigned short* agg_s = (unsigned short*)(smem + 49152); // [128][64] agg
    unsigned short* hbuf  = (unsigned short*)(smem + 65536) + wv * 1024; // per-wave [32][32]
    float* inj_s = (float*)(smem + 49152);                   // aliases agg region (phase 0 only)

    // ---------------- Phase 0: injection ----------------
    if (tid < 128) {
        const float* iwr = injw + (c * 128 + tid) * 64;
        const float* xr = x + cell * 64;
        float acc = injb[c * 128 + tid];
        #pragma unroll
        for (int d4 = 0; d4 < 16; ++d4) {
            float4 a = ((const float4*)iwr)[d4];
            float4 xv = ((const float4*)xr)[d4];
            acc += a.x * xv.x + a.y * xv.y + a.z * xv.z + a.w * xv.w;
        }
        inj_s[tid] = acc;
    }
    __syncthreads();   // B1: inj ready

    // ---------------- stage h_id (own wave rows) ----------------
    {
        const int row = wv * 32 + (lane >> 1);
        const int colbase = (lane & 1) * 32;
        const float* hr = h + (size_t)(cell * 128 + row) * 64;
        const float* nr = nid + (size_t)(c * 128 + row) * 64;
        #pragma unroll
        for (int g = 0; g < 4; ++g) {
            int col = colbase + g * 8;
            float4 a0 = *(const float4*)(hr + col);
            float4 a1 = *(const float4*)(hr + col + 4);
            float4 n0 = *(const float4*)(nr + col);
            float4 n1 = *(const float4*)(nr + col + 4);
            float v[8] = {a0.x, a0.y, a0.z, a0.w, a1.x, a1.y, a1.z, a1.w};
            float nn[8] = {n0.x, n0.y, n0.z, n0.w, n1.x, n1.y, n1.z, n1.w};
            unsigned short us[8];
            #pragma unroll
            for (int j = 0; j < 8; ++j) {
                float hv = v[j];
                if (row < 2) hv += inj_s[row * 64 + col + j];   // injection into first ALPHA neurons
                hv += nn[j];
                us[j] = f2bf(hv);
            }
            *(bf16x8*)&hid_s[sw64(row, col)] = *(bf16x8*)us;
        }
    }
    // no barrier: all subsequent A-operand reads of hid_s are own-wave rows

    // A-frags of h_id (reused for msg-L1 and state-L1 k<64)
    bf16x8 aH[2][2];
    #pragma unroll
    for (int rt = 0; rt < 2; ++rt)
        #pragma unroll
        for (int ks = 0; ks < 2; ++ks)
            aH[rt][ks] = *(const bf16x8*)&hid_s[sw64(wv * 32 + rt * 16 + lr, ks * 32 + lg * 8)];

    // ---------------- msg MLP: m = tanh(h_id@w1m^T+b)@w2m^T+b ----------------
    f32x4 accM[2][4];
    #pragma unroll
    for (int rt = 0; rt < 2; ++rt)
        #pragma unroll
        for (int dt = 0; dt < 4; ++dt)
            accM[rt][dt] = (f32x4){0.f, 0.f, 0.f, 0.f};

    #pragma unroll
    for (int ch = 0; ch < 4; ++ch) {          // 32 hidden units per chunk
        f32x4 accH[2][2];
        #pragma unroll
        for (int rt = 0; rt < 2; ++rt)
            #pragma unroll
            for (int ht = 0; ht < 2; ++ht)
                accH[rt][ht] = (f32x4){0.f, 0.f, 0.f, 0.f};
        #pragma unroll
        for (int ks = 0; ks < 2; ++ks)
            #pragma unroll
            for (int ht = 0; ht < 2; ++ht) {
                bf16x8 bw = *(const bf16x8*)&w1m[(ch * 32 + ht * 16 + lr) * 64 + ks * 32 + lg * 8];
                #pragma unroll
                for (int rt = 0; rt < 2; ++rt)
                    accH[rt][ht] = MFMA(aH[rt][ks], bw, accH[rt][ht]);
            }
        #pragma unroll
        for (int rt = 0; rt < 2; ++rt)
            #pragma unroll
            for (int ht = 0; ht < 2; ++ht) {
                float b1v = mb1[ch * 32 + ht * 16 + lr];
                #pragma unroll
                for (int r = 0; r < 4; ++r) {
                    float t = tanhf(accH[rt][ht][r] + b1v);
                    hbuf[sw32(rt * 16 + lg * 4 + r, ht * 16 + lr)] = f2bf(t);
                }
            }
        #pragma unroll
        for (int rt = 0; rt < 2; ++rt) {
            bf16x8 aM = *(const bf16x8*)&hbuf[sw32(rt * 16 + lr, lg * 8)];
            #pragma unroll
            for (int dt = 0; dt < 4; ++dt) {
                bf16x8 bw = *(const bf16x8*)&w2m[(dt * 16 + lr) * 128 + ch * 32 + lg * 8];
                accM[rt][dt] = MFMA(aM, bw, accM[rt][dt]);
            }
        }
    }
    // epilogue: +b2, write m (global f32 out) + m_s + mT_s (bf16)
    #pragma unroll
    for (int rt = 0; rt < 2; ++rt)
        #pragma unroll
        for (int dt = 0; dt < 4; ++dt) {
            float b2v = mb2[dt * 16 + lr];
            #pragma unroll
            for (int r = 0; r < 4; ++r) {
                float mv = accM[rt][dt][r] + b2v;
                int n = wv * 32 + rt * 16 + lg * 4 + r;
                int dcol = dt * 16 + lr;
                out_m[(size_t)(cell * 128 + n) * 64 + dcol] = mv;
                unsigned short mb = f2bf(mv);
                m_s[sw64(n, dcol)] = mb;
                mT_s[sw128(dcol, n)] = mb;
            }
        }
    __syncthreads();   // B3: m_s/mT_s visible to all waves

    // ---------------- agg = W @ m ----------------
    f32x4 accA[2][4];
    #pragma unroll
    for (int rt = 0; rt < 2; ++rt)
        #pragma unroll
        for (int dt = 0; dt < 4; ++dt)
            accA[rt][dt] = (f32x4){0.f, 0.f, 0.f, 0.f};
    {
        const float* Wbase = W + (size_t)cell * 128 * 128;
        #pragma unroll
        for (int ks = 0; ks < 4; ++ks)
            #pragma unroll
            for (int rt = 0; rt < 2; ++rt) {
                const float* wr = Wbase + (wv * 32 + rt * 16 + lr) * 128 + ks * 32 + lg * 8;
                float4 wa = *(const float4*)wr;
                float4 wb = *(const float4*)(wr + 4);
                unsigned short uw[8] = {f2bf(wa.x), f2bf(wa.y), f2bf(wa.z), f2bf(wa.w),
                                        f2bf(wb.x), f2bf(wb.y), f2bf(wb.z), f2bf(wb.w)};
                bf16x8 aW = *(bf16x8*)uw;
                #pragma unroll
                for (int dt = 0; dt < 4; ++dt) {
                    bf16x8 bm = *(const bf16x8*)&mT_s[sw128(dt * 16 + lr, ks * 32 + lg * 8)];
                    accA[rt][dt] = MFMA(aW, bm, accA[rt][dt]);
                }
            }
    }
    #pragma unroll
    for (int rt = 0; rt < 2; ++rt)
        #pragma unroll
        for (int dt = 0; dt < 4; ++dt)
            #pragma unroll
            for (int r = 0; r < 4; ++r)
                agg_s[sw64(wv * 32 + rt * 16 + lg * 4 + r, dt * 16 + lr)] = f2bf(accA[rt][dt][r]);
    // own-wave rows only -> no barrier

    // ---------------- state MLP: dh = tanh([h_id|agg]@w1s^T+b)@w2s^T+b ----------------
    bf16x8 aG[2][2];
    #pragma unroll
    for (int rt = 0; rt < 2; ++rt)
        #pragma unroll
        for (int ks = 0; ks < 2; ++ks)
            aG[rt][ks] = *(const bf16x8*)&agg_s[sw64(wv * 32 + rt * 16 + lr, ks * 32 + lg * 8)];

    f32x4 accD[2][4];
    #pragma unroll
    for (int rt = 0; rt < 2; ++rt)
        #pragma unroll
        for (int dt = 0; dt < 4; ++dt)
            accD[rt][dt] = (f32x4){0.f, 0.f, 0.f, 0.f};

    #pragma unroll
    for (int ch = 0; ch < 8; ++ch) {          // 32 of 256 hidden units per chunk
        f32x4 accS[2][2];
        #pragma unroll
        for (int rt = 0; rt < 2; ++rt)
            #pragma unroll
            for (int ht = 0; ht < 2; ++ht)
                accS[rt][ht] = (f32x4){0.f, 0.f, 0.f, 0.f};
        #pragma unroll
        for (int ks = 0; ks < 4; ++ks)
            #pragma unroll
            for (int ht = 0; ht < 2; ++ht) {
                bf16x8 bw = *(const bf16x8*)&w1s[(ch * 32 + ht * 16 + lr) * 128 + ks * 32 + lg * 8];
                #pragma unroll
                for (int rt = 0; rt < 2; ++rt) {
                    bf16x8 af = (ks < 2) ? aH[rt][ks] : aG[rt][ks - 2];
                    accS[rt][ht] = MFMA(af, bw, accS[rt][ht]);
                }
            }
        #pragma unroll
        for (int rt = 0; rt < 2; ++rt)
            #pragma unroll
            for (int ht = 0; ht < 2; ++ht) {
                float bv = sb1[ch * 32 + ht * 16 + lr];
                #pragma unroll
                for (int r = 0; r < 4; ++r) {
                    float t = tanhf(accS[rt][ht][r] + bv);
                    hbuf[sw32(rt * 16 + lg * 4 + r, ht * 16 + lr)] = f2bf(t);
                }
            }
        #pragma unroll
        for (int rt = 0; rt < 2; ++rt) {
            bf16x8 aS = *(const bf16x8*)&hbuf[sw32(rt * 16 + lr, lg * 8)];
            #pragma unroll
            for (int dt = 0; dt < 4; ++dt) {
                bf16x8 bw = *(const bf16x8*)&w2s[(dt * 16 + lr) * 256 + ch * 32 + lg * 8];
                accD[rt][dt] = MFMA(aS, bw, accD[rt][dt]);
            }
        }
    }

    // ---------------- decay_new, h_new ----------------
    float dnew_r[2][4];
    #pragma unroll
    for (int rt = 0; rt < 2; ++rt)
        #pragma unroll
        for (int r = 0; r < 4; ++r) {
            float s = 0.f;
            #pragma unroll
            for (int dt = 0; dt < 4; ++dt) {
                accD[rt][dt][r] += sb2[dt * 16 + lr];
                s += accD[rt][dt][r];
            }
            s += __shfl_xor(s, 1);
            s += __shfl_xor(s, 2);
            s += __shfl_xor(s, 4);
            s += __shfl_xor(s, 8);
            int row = wv * 32 + rt * 16 + lg * 4 + r;
            float mean = s * (1.0f / 64.0f);
            float dg = 0.5f * sigm(dgl[c * 128 + row]);
            float dn = (1.0f - dg) * decay[cell * 128 + row] + dg * sigm(mean);
            if (lr == 0) out_d[cell * 128 + row] = dn;
            dnew_r[rt][r] = dn;
        }
    #pragma unroll
    for (int rt = 0; rt < 2; ++rt)
        #pragma unroll
        for (int r = 0; r < 4; ++r) {
            int row = wv * 32 + rt * 16 + lg * 4 + r;
            float dn = dnew_r[rt][r];
            #pragma unroll
            for (int dt = 0; dt < 4; ++dt) {
                int col = dt * 16 + lr;
                float hpost = bf2f(hid_s[sw64(row, col)]) - nid[(size_t)(c * 128 + row) * 64 + col];
                float hn = (1.0f - dn) * hpost + dn * tanhf(accD[rt][dt][r]);
                out_h[(size_t)(cell * 128 + row) * 64 + col] = hn;
                hid_s[sw64(row, col)] = f2bf(hn);   // h_new for outer product
            }
        }
    // own-wave rows only; m_s unchanged since B3 -> no barrier

    // ---------------- outer = h_new @ m^T / 64 ; hebbian/W update ----------------
    bf16x8 aO[2][2];
    #pragma unroll
    for (int rt = 0; rt < 2; ++rt)
        #pragma unroll
        for (int ks = 0; ks < 2; ++ks)
            aO[rt][ks] = *(const bf16x8*)&hid_s[sw64(wv * 32 + rt * 16 + lr, ks * 32 + lg * 8)];

    f32x4 accO[2][8];
    #pragma unroll
    for (int rt = 0; rt < 2; ++rt)
        #pragma unroll
        for (int jt = 0; jt < 8; ++jt)
            accO[rt][jt] = (f32x4){0.f, 0.f, 0.f, 0.f};
    #pragma unroll
    for (int jt = 0; jt < 8; ++jt)
        #pragma unroll
        for (int ks = 0; ks < 2; ++ks) {
            bf16x8 bm = *(const bf16x8*)&m_s[sw64(jt * 16 + lr, ks * 32 + lg * 8)];
            #pragma unroll
            for (int rt = 0; rt < 2; ++rt)
                accO[rt][jt] = MFMA(aO[rt][ks], bm, accO[rt][jt]);
        }

    #pragma unroll
    for (int rt = 0; rt < 2; ++rt)
        #pragma unroll
        for (int r = 0; r < 4; ++r) {
            int i = wv * 32 + rt * 16 + lg * 4 + r;
            float hg = 0.5f * sigm(hdl[c * 128 + i]);
            float wg = 0.5f * sigm(wdl[c * 128 + i]);
            const float* hbr = hebb + (size_t)(cell * 128 + i) * 128;
            const float* Wr = W + (size_t)(cell * 128 + i) * 128;
            float* ohb = out_hb + (size_t)(cell * 128 + i) * 128;
            float wpre[8];
            float ss = 0.f;
            #pragma unroll
            for (int jt = 0; jt < 8; ++jt) {
                int j = jt * 16 + lr;
                float o = accO[rt][jt][r] * (1.0f / 64.0f);
                float hbn = (1.0f - hg) * hbr[j] + hg * o;
                ohb[j] = hbn;
                float wp = (1.0f - wg) * Wr[j] + wg * hbn;
                wpre[jt] = wp;
                ss += wp * wp;
            }
            ss += __shfl_xor(ss, 1);
            ss += __shfl_xor(ss, 2);
            ss += __shfl_xor(ss, 4);
            ss += __shfl_xor(ss, 8);
            float scale = rsqrtf(ss * (1.0f / 128.0f) + 1e-6f);
            float* oW = out_W + (size_t)(cell * 128 + i) * 128;
            #pragma unroll
            for (int jt = 0; jt < 8; ++jt)
                oW[jt * 16 + lr] = wpre[jt] * scale;
        }
}

extern "C" void kernel_launch(void* const* d_in, const int* in_sizes, int n_in,
                              void* d_out, int out_size, void* d_ws, size_t ws_size,
                              hipStream_t stream) {
    const float* x    = (const float*)d_in[0];
    const float* h    = (const float*)d_in[1];
    const float* W    = (const float*)d_in[2];
    const float* dec  = (const float*)d_in[3];
    const float* hebb = (const float*)d_in[4];
    const float* nid  = (const float*)d_in[5];
    const float* sw1  = (const float*)d_in[6];
    const float* sb1  = (const float*)d_in[7];
    const float* sw2  = (const float*)d_in[8];
    const float* sb2  = (const float*)d_in[9];
    const float* mw1  = (const float*)d_in[10];
    const float* mb1  = (const float*)d_in[11];
    const float* mw2  = (const float*)d_in[12];
    const float* mb2  = (const float*)d_in[13];
    const float* injw = (const float*)d_in[14];
    const float* injb = (const float*)d_in[15];
    const float* wdl  = (const float*)d_in[16];
    const float* dgl  = (const float*)d_in[17];
    const float* hdl  = (const float*)d_in[18];

    unsigned short* wbf = (unsigned short*)d_ws;   // 65536 bf16 = 128 KB

    cvt_w<<<256, 256, 0, stream>>>(mw1, mw2, sw1, sw2, wbf);
    cell_kernel<<<2048, 256, 0, stream>>>(x, h, W, dec, hebb, nid, sb1, sb2, mb1, mb2,
                                          injw, injb, wdl, dgl, hdl, wbf, (float*)d_out);
}